// Round 7
// baseline (22.010 us; speedup 1.0000x reference)
//
#include <hip/hip_runtime.h>

// Problem geometry (f32):
//   x:   [8, 16, 3, 224, 224]
//   out: [8, 16, 224, 224, 3]  (permute 0,1,4,3,2)
// batch 0: y[0]=x[0]; y[t] = x[t] - 0.4*y[t-1] + 3   (elementwise c,h,w)
// batches 1..6: zeros
// batch 7: z[0]=0; z[t] = 3 - 0.4*z[t-1], broadcast over (w,h,c)
//
// Round 7: line-exact batch-0 writes. h-tile=32 makes each (t,w) store piece
// 32h*3c*4B = 384 B = exactly 3 aligned 128-B lines at offset 384k -> no
// partial-line L2 writes (write-allocate fetch theory) and every line has
// exactly ONE writer block. Tile = 32h x 32w x 16t: 49 blocks x ~393 KB
// ~= one CU-share each. Tiles at bid%41 (coprime to 8 -> uniform XCDs).
// 2-t LDS slab (24 KB) + rotate swizzle (verified r5/r6), prefetch-1-phase.

typedef float fx4 __attribute__((ext_vector_type(4)));

#define SP        150528    // 3*224*224 elements per (b,t) slice
#define TT        16
#define CH_STRIDE 50176     // 224*224
#define BSTRIDE   2408448   // 16*SP elements per batch

#define NWT2   7            // 224/32 tiles per axis
#define NTILES 49           // 7x7
#define TSPREAD 41          // coprime to 8; 41*48=1968 < 2048

#define FILL4   4214784     // 7 * 16*SP/4 vec4s (batches 1..7)
#define TSLICE4 37632       // SP/4
#define NBLOCKS 2048
#define NFILL   (NBLOCKS - NTILES)   // 1999
#define RFILL   2109                 // ceil(FILL4/NFILL)

__global__ __launch_bounds__(256) void temporal_fused(
    const float* __restrict__ x, float* __restrict__ out)
{
    const int tid = threadIdx.x;
    const int bid = blockIdx.x;

    // 24 KB: 2 t-slices of [32 w][96 floats (32h x 3c, slot-swizzled)]
    __shared__ float lds[2 * 32 * 96];

    const bool is_tile = (bid % TSPREAD == 0) && (bid / TSPREAD) < NTILES;

    if (is_tile) {
        // ---------- batch-0 recurrence, tile = 32h x 32w, 4 pts/thread ----
        const int tileid = bid / TSPREAD;
        const int h0 = (tileid / NWT2) * 32;
        const int w0 = (tileid % NWT2) * 32;
        const int dw = tid & 31;       // w offset 0..31
        const int hq = tid >> 5;       // 0..7; owns hh = hq*4 + i, i=0..3

        int rbase[4];
        #pragma unroll
        for (int i = 0; i < 4; ++i)
            rbase[i] = (h0 + hq * 4 + i) * 224 + w0 + dw;

        // LDS write offsets (rotate swizzle by w over 24 fx4 slots per run)
        int woff[4][3];
        #pragma unroll
        for (int i = 0; i < 4; ++i) {
            #pragma unroll
            for (int c = 0; c < 3; ++c) {
                const int idx = (hq * 4 + i) * 3 + c;     // 0..95
                const int s = idx >> 2, o = idx & 3;
                woff[i][c] = dw * 96 + ((s + dw) % 24) * 4 + o;
            }
        }

        float y[4][3];
        float xc[2][4][3], xn[2][4][3];
        // preload phase 0 (t = 0,1): 24 independent loads
        #pragma unroll
        for (int tp = 0; tp < 2; ++tp)
            #pragma unroll
            for (int i = 0; i < 4; ++i)
                #pragma unroll
                for (int c = 0; c < 3; ++c)
                    xc[tp][i][c] = x[tp * SP + c * CH_STRIDE + rbase[i]];

        const int ob0 = w0 * 672 + h0 * 3;   // floats; 672 floats per (t,w) run

        #pragma unroll
        for (int p = 0; p < 8; ++p) {
            // prefetch next phase (hide HBM latency under compute+readout)
            if (p < 7) {
                #pragma unroll
                for (int tp = 0; tp < 2; ++tp)
                    #pragma unroll
                    for (int i = 0; i < 4; ++i)
                        #pragma unroll
                        for (int c = 0; c < 3; ++c)
                            xn[tp][i][c] =
                                x[((p + 1) * 2 + tp) * SP + c * CH_STRIDE + rbase[i]];
            }
            // advance recurrence for t = 2p, 2p+1; stage into LDS
            #pragma unroll
            for (int tp = 0; tp < 2; ++tp) {
                const int t = p * 2 + tp;
                #pragma unroll
                for (int i = 0; i < 4; ++i) {
                    #pragma unroll
                    for (int c = 0; c < 3; ++c) {
                        const float xv = xc[tp][i][c];
                        y[i][c] = (t == 0) ? xv : (xv - 0.4f * y[i][c] + 3.0f);
                        lds[tp * 3072 + woff[i][c]] = y[i][c];
                    }
                }
            }
            __syncthreads();

            // readout: 2t x 32w x 24 fx4 = 1536 fx4 = 6 iters x 256 thr.
            // Each (t,w) piece = 384 B = 3 full aligned lines.
            const fx4* lds4 = reinterpret_cast<const fx4*>(lds);
            #pragma unroll
            for (int k = 0; k < 6; ++k) {
                const int j = tid + k * 256;        // < 1536
                const int tp = j >> 9 >> 0 ? (j / 768) : 0; // j/768
                const int jt = j / 768;
                const int r = j - jt * 768;
                const int w = r / 24;
                const int piece = r - w * 24;
                const int phys = (piece + w) % 24;
                const fx4 f4 = lds4[jt * 768 + w * 24 + phys];
                *reinterpret_cast<fx4*>(
                    out + (p * 2 + jt) * SP + ob0 + w * 672 + piece * 4) = f4;
            }
            __syncthreads();   // protect LDS before next phase overwrites

            // rotate prefetch buffers
            #pragma unroll
            for (int tp = 0; tp < 2; ++tp)
                #pragma unroll
                for (int i = 0; i < 4; ++i)
                    #pragma unroll
                    for (int c = 0; c < 3; ++c)
                        xc[tp][i][c] = xn[tp][i][c];
        }
        return;
    }

    // ---------------- fill: batches 1..6 zeros, batch 7 broadcast z[t] ----
    const int tiles_before = min((bid + TSPREAD - 1) / TSPREAD, NTILES);
    const int fidx = bid - tiles_before;          // 0..NFILL-1

    fx4* out4 = reinterpret_cast<fx4*>(out + BSTRIDE); // batch-1 start
    int q   = fidx * RFILL;
    int end = q + RFILL;
    if (end > FILL4) end = FILL4;

    while (q < end) {
        const int slice = q / TSLICE4;            // 0..111 = (batch-1)*16 + t
        int send = (slice + 1) * TSLICE4;
        if (send > end) send = end;
        float zv = 0.0f;
        if ((slice >> 4) == 6) {                  // batch 7
            const int t = slice & 15;
            float z = 0.0f;
            for (int i = 0; i < t; ++i) z = 3.0f - 0.4f * z;
            zv = z;
        }
        fx4 val;
        val.x = zv; val.y = zv; val.z = zv; val.w = zv;
        for (int i = q + tid; i < send; i += 256)
            out4[i] = val;
        q = send;
    }
}

extern "C" void kernel_launch(void* const* d_in, const int* in_sizes, int n_in,
                              void* d_out, int out_size, void* d_ws, size_t ws_size,
                              hipStream_t stream) {
    const float* x = (const float*)d_in[0];
    float* out = (float*)d_out;
    temporal_fused<<<NBLOCKS, 256, 0, stream>>>(x, out);
}

// Round 8
// 17.960 us; speedup vs baseline: 1.2255x; 1.2255x over previous
//
#include <hip/hip_runtime.h>

// Problem geometry (f32):
//   x:   [8, 16, 3, 224, 224]
//   out: [8, 16, 224, 224, 3]  (permute 0,1,4,3,2)
// batch 0: y[0]=x[0]; y[t] = x[t] - 0.4*y[t-1] + 3   (elementwise c,h,w)
// batches 1..6: zeros
// batch 7: z[0]=0; z[t] = 3 - 0.4*z[t-1], broadcast over (w,h,c)
//
// Round 8: line-exact batch-0 writes WITHOUT round-7's serialization.
//  - 512-thread blocks, tile = 32h x 16w, 1 point/thread, ALL 48 loads
//    issued before the first barrier (round-7 regressed because per-phase
//    prefetch + __syncthreads -> vmcnt(0) drained every phase).
//  - Piece per (t,w) = 32h*3c*4B = 384 B at byte offset 384k of the 2688-B
//    run -> exactly 3 aligned 128-B lines, single writer block (vs round-6's
//    line-straddling 96-B pieces from 4 XCDs -> DRAM page thrash).
//  - 4 t-phases through 24 KB LDS, rotate-by-w swizzle over 24 fx4 slots
//    (verified absmax=0 in r5/r6/r7).
//  - 98 tile blocks @197KB vs 512-block share 169KB: imbalance 1.16x
//    (round 6: 2.3x). Tiles at bid%5 (coprime to 8 -> uniform XCDs).

typedef float fx4 __attribute__((ext_vector_type(4)));

#define SP        150528    // 3*224*224 elements per (b,t) slice
#define TT        16
#define CH_STRIDE 50176     // 224*224
#define BSTRIDE   2408448   // 16*SP elements per batch

#define NWT    14           // 224/16 w-tiles
#define NTILES 98           // 7 h-tiles x 14 w-tiles
#define TSPREAD 5           // coprime to 8; 5*97=485 < 512

#define FILL4   4214784     // 7 * 16*SP/4 vec4s (batches 1..7)
#define TSLICE4 37632       // SP/4
#define NBLOCKS 512
#define NFILL   (NBLOCKS - NTILES)   // 414
#define RFILL   10181                // ceil(FILL4/NFILL)

__global__ __launch_bounds__(512) void temporal_fused(
    const float* __restrict__ x, float* __restrict__ out)
{
    const int tid = threadIdx.x;
    const int bid = blockIdx.x;

    // 24 KB: 4 t-slices of [16 w][96 floats (32h x 3c, rotate-swizzled)]
    __shared__ float lds[4 * 16 * 96];

    const bool is_tile = (bid % TSPREAD == 0) && (bid / TSPREAD) < NTILES;

    if (is_tile) {
        // -------- batch-0 recurrence, tile = 32h x 16w, 1 point/thread ----
        const int tileid = bid / TSPREAD;
        const int h0 = (tileid / NWT) * 32;
        const int w0 = (tileid % NWT) * 16;
        const int dw = tid & 15;       // w offset 0..15
        const int hh = tid >> 4;       // h offset 0..31
        const int rbase = (h0 + hh) * 224 + w0 + dw;

        // ALL 48 loads independent, before any barrier -> one HBM latency
        float v[TT][3];
        #pragma unroll
        for (int t = 0; t < TT; ++t) {
            #pragma unroll
            for (int c = 0; c < 3; ++c)
                v[t][c] = x[t * SP + c * CH_STRIDE + rbase];
        }

        // LDS write offsets: logical idx = hh*3+c in [0,96); slot s=idx>>2,
        // phys slot = (s+dw)%24 (rotate swizzle, alignment-preserving)
        int woff[3];
        #pragma unroll
        for (int c = 0; c < 3; ++c) {
            const int idx = hh * 3 + c;
            const int s = idx >> 2, o = idx & 3;
            woff[c] = dw * 96 + ((s + dw) % 24) * 4 + o;
        }

        const int ob0 = w0 * 672 + h0 * 3;
        float y0 = 0.f, y1 = 0.f, y2 = 0.f;

        #pragma unroll
        for (int p = 0; p < 4; ++p) {
            // advance recurrence for t = 4p..4p+3; stage into LDS
            #pragma unroll
            for (int tp = 0; tp < 4; ++tp) {
                const int t = p * 4 + tp;
                if (t == 0) { y0 = v[0][0]; y1 = v[0][1]; y2 = v[0][2]; }
                else {
                    y0 = v[t][0] - 0.4f * y0 + 3.0f;
                    y1 = v[t][1] - 0.4f * y1 + 3.0f;
                    y2 = v[t][2] - 0.4f * y2 + 3.0f;
                }
                lds[tp * 1536 + woff[0]] = y0;
                lds[tp * 1536 + woff[1]] = y1;
                lds[tp * 1536 + woff[2]] = y2;
            }
            __syncthreads();

            // readout: 4t x 16w x 24 fx4 = 1536 fx4 = 3 iters x 512 thr.
            // Each (t,w) piece = 384 B = 3 full aligned 128-B lines.
            const fx4* lds4 = reinterpret_cast<const fx4*>(lds);
            #pragma unroll
            for (int k = 0; k < 3; ++k) {
                const int j = tid + k * 512;        // < 1536
                const int jt = j / 384;             // t within phase
                const int r = j - jt * 384;
                const int w = r / 24;
                const int piece = r - w * 24;
                const int phys = (piece + w) % 24;
                const fx4 f4 = lds4[jt * 384 + w * 24 + phys];
                *reinterpret_cast<fx4*>(
                    out + (p * 4 + jt) * SP + ob0 + w * 672 + piece * 4) = f4;
            }
            __syncthreads();   // protect LDS before next phase overwrites
        }
        return;
    }

    // ---------------- fill: batches 1..6 zeros, batch 7 broadcast z[t] ----
    const int tiles_before = min((bid + TSPREAD - 1) / TSPREAD, NTILES);
    const int fidx = bid - tiles_before;          // 0..NFILL-1

    fx4* out4 = reinterpret_cast<fx4*>(out + BSTRIDE); // batch-1 start
    int q   = fidx * RFILL;
    int end = q + RFILL;
    if (end > FILL4) end = FILL4;

    while (q < end) {
        const int slice = q / TSLICE4;            // 0..111 = (batch-1)*16 + t
        int send = (slice + 1) * TSLICE4;
        if (send > end) send = end;
        float zv = 0.0f;
        if ((slice >> 4) == 6) {                  // batch 7
            const int t = slice & 15;
            float z = 0.0f;
            for (int i = 0; i < t; ++i) z = 3.0f - 0.4f * z;
            zv = z;
        }
        fx4 val;
        val.x = zv; val.y = zv; val.z = zv; val.w = zv;
        for (int i = q + tid; i < send; i += 512)
            out4[i] = val;
        q = send;
    }
}

extern "C" void kernel_launch(void* const* d_in, const int* in_sizes, int n_in,
                              void* d_out, int out_size, void* d_ws, size_t ws_size,
                              hipStream_t stream) {
    const float* x = (const float*)d_in[0];
    float* out = (float*)d_out;
    temporal_fused<<<NBLOCKS, 512, 0, stream>>>(x, out);
}